// Round 1
// baseline (73.505 us; speedup 1.0000x reference)
//
#include <hip/hip_runtime.h>

// ROI head matcher. R5: move GT records out of LDS into SGPRs.
// Theory: R4's inner loop carried 2 wave-uniform LDS reads per GT
// (ds_read_b128 + ds_read_b32) through the CU-shared LDS pipe with an
// lgkmcnt dependency every iteration -> ~4.5x above the ~7us VALU-issue
// floor. GT data is wave-uniform, so it belongs in SGPRs: a 1-block prep
// kernel packs {x1,y1,x2,y2,area,label,0,0} per GT into d_ws (4KB), and
// the main loop does one s_load_dwordx8 per GT (address forced uniform by
// readfirstlane on the wave id). Every VALU op reads <=1 SGPR operand
// (v_max_f32 v,s,v etc.; uni = (area_p + s_area) - inter). The inner loop
// now contains ZERO vector-memory/LDS instructions. s_rec staging and its
// barrier are gone; epilogue gathers label/box from the L1-resident record
// buffer in global memory.
//
// Decomposition unchanged from R4 (validated absmax 0): block 256 = 4
// waves, lane <-> proposal (64/block), wave w scans GTs [32w,32w+32) with
// a partial exact argmax; partials combined by wave 0 via LDS in
// ascending-g order (strict '>' preserves first-index semantics; sentinel
// (0,1,g0) is an in-range iou-0 candidate so all-zero rows resolve to
// g=0 like jnp.argmax).
//
// Argmax compare: exact Dekker cross-product (validated absmax 0 R2-R4):
//   inter_g/uni_g > inter_b/uni_b  <=>  (p1+e1) > (p2+e2), e = fmaf(a,b,-p)
// One IEEE divide in the epilogue reproduces best_match_iou bit-exactly.

#define BLOCK 256
#define NPROP 64            // proposals per block
#define GT_TOTAL 128
#define GT_PER_WAVE 32
#define IOU_THRESHOLD 0.5f
#define LOW_BG_IOU 0.1f

typedef __attribute__((ext_vector_type(8))) float float8;

__global__ __launch_bounds__(GT_TOTAL) void prep_kernel(
    const float* __restrict__ gt_boxes,   // [G,4]
    const int*   __restrict__ gt_labels,  // [G]
    float*       __restrict__ rec)        // [G,8] packed records
{
#pragma clang fp contract(off)
    int g = threadIdx.x;
    float4 b = ((const float4*)gt_boxes)[g];
    float8 r;
    r[0] = b.x; r[1] = b.y; r[2] = b.z; r[3] = b.w;
    r[4] = (b.z - b.x) * (b.w - b.y);     // area, rounded like ref
    r[5] = (float)gt_labels[g];
    r[6] = 0.0f; r[7] = 0.0f;
    ((float8*)rec)[g] = r;
}

__global__ __launch_bounds__(BLOCK) void roi_match_kernel(
    const float* __restrict__ proposals,  // [N,4]
    const float* __restrict__ rec,        // [G,8] packed (from prep)
    float* __restrict__ out,              // [N] labels then [N,4] boxes
    int N)
{
#pragma clang fp contract(off)
    __shared__ float4 s_part[4][NPROP];   // inter, uni, bi(bits), pad

    int tid  = threadIdx.x;
    int wave = __builtin_amdgcn_readfirstlane(tid >> 6);  // uniform -> SGPR
    int lane = tid & 63;
    int n  = blockIdx.x * NPROP + lane;
    int nc = n < N ? n : N - 1;           // clamp loads; writes are guarded

    float4 p = ((const float4*)proposals)[nc];
    float area_p = (p.z - p.x) * (p.w - p.y);

    int g0 = wave * GT_PER_WAVE;
    int   bi = g0;                        // sentinel: iou 0 at first g of range
    float inter_b = 0.0f, uni_b = 1.0f;

#pragma unroll 4
    for (int j = 0; j < GT_PER_WAVE; ++j) {
        int g = g0 + j;                   // wave-uniform -> s_load_dwordx8
        float8 r = ((const float8*)rec)[g];

        float x1 = fmaxf(r[0], p.x);      // v_max_f32 v, s, v (1 SGPR each)
        float y1 = fmaxf(r[1], p.y);
        float x2 = fminf(r[2], p.z);
        float y2 = fminf(r[3], p.w);
        float iw = fmaxf(x2 - x1, 0.0f);
        float ih = fmaxf(y2 - y1, 0.0f);
        float inter = iw * ih;
        float uni   = (area_p + r[4]) - inter;  // add(v,s) then sub(v,v)

        float p1 = inter * uni_b;
        float e1 = fmaf(inter, uni_b, -p1);
        float p2 = inter_b * uni;
        float e2 = fmaf(inter_b, uni, -p2);
        bool gt = (p1 - p2) > (e2 - e1);  // exact P1 > P2

        bi      = gt ? g     : bi;
        inter_b = gt ? inter : inter_b;
        uni_b   = gt ? uni   : uni_b;
    }

    s_part[wave][lane] = make_float4(inter_b, uni_b, __int_as_float(bi), 0.0f);
    __syncthreads();

    if (wave == 0 && n < N) {
        float4 b0 = s_part[0][lane];
        float binter = b0.x, buni = b0.y;
        int   bbi = __float_as_int(b0.z);
#pragma unroll
        for (int w = 1; w < 4; ++w) {     // ascending g-range order
            float4 c = s_part[w][lane];
            float ci = c.x, cu = c.y;
            float p1 = ci * buni;
            float e1 = fmaf(ci, buni, -p1);
            float p2 = binter * cu;
            float e2 = fmaf(binter, cu, -p2);
            bool gt = (p1 - p2) > (e2 - e1);
            bbi    = gt ? __float_as_int(c.z) : bbi;
            binter = gt ? ci : binter;
            buni   = gt ? cu : buni;
        }

        float best = binter / buni;       // IEEE div, matches reference max

        // gather label + box from the 4KB record buffer (L1-resident)
        float4 box = ((const float4*)rec)[bbi * 2];
        float glab = rec[bbi * 8 + 5];

        float lab;
        if (best < LOW_BG_IOU)          lab = -1.0f;   // ignored
        else if (best < IOU_THRESHOLD)  lab = 0.0f;    // background
        else                            lab = glab;    // gt label

        out[n] = lab;
        ((float4*)(out + N))[n] = box;
    }
}

extern "C" void kernel_launch(void* const* d_in, const int* in_sizes, int n_in,
                              void* d_out, int out_size, void* d_ws, size_t ws_size,
                              hipStream_t stream) {
    const float* proposals = (const float*)d_in[0];
    const float* gt_boxes  = (const float*)d_in[1];
    const int*   gt_labels = (const int*)d_in[2];
    float* out = (float*)d_out;
    float* rec = (float*)d_ws;             // 4KB of the workspace

    int N = in_sizes[0] / 4;               // 200000
    int blocks = (N + NPROP - 1) / NPROP;  // 3125 (exact)

    prep_kernel<<<1, GT_TOTAL, 0, stream>>>(gt_boxes, gt_labels, rec);
    roi_match_kernel<<<blocks, BLOCK, 0, stream>>>(proposals, rec, out, N);
}